// Round 15
// baseline (487.204 us; speedup 1.0000x reference)
//
#include <hip/hip_runtime.h>

// ---------- types ----------
typedef short s16x8 __attribute__((ext_vector_type(8)));   // 8 bf16 (4 VGPRs)
typedef float f32x4 __attribute__((ext_vector_type(4)));

static __device__ __forceinline__ unsigned short f2bf(float f) {
  unsigned u = __builtin_bit_cast(unsigned, f);
  return (unsigned short)((u + 0x7FFFu + ((u >> 16) & 1u)) >> 16);   // RNE; finite
}

// async global->LDS, 16B per lane; LDS dst is wave-uniform base + lane*16
#define GLL16(G, L) __builtin_amdgcn_global_load_lds( \
    (const __attribute__((address_space(1))) void*)(G), \
    (__attribute__((address_space(3))) void*)(L), 16, 0, 0)

#define KD 512
// B=16, T=512, C=19, E=512, H=8, HD=64; groups = 8192, rows = 155648 = 1216*128.
// Fragment layout: frag (tile16, ktile32) = 1 KB: lane lf = (row&15) + 16*jc holds
// 16 B (8 bf16) of [row][ktile*32 + jc*8]. MFMA A/B reads are lane*16-linear.

// ---------- kernel: eeg fp32 -> bf16 fragment layout ----------
__global__ __launch_bounds__(256)
void k_conva(const float* __restrict__ src, unsigned short* __restrict__ dst) {
  int gid = blockIdx.x * 256 + threadIdx.x;
  int mt = gid >> 10, slot = gid & 1023;
  int kt = slot >> 6, lf = slot & 63;
  int row = mt * 16 + (lf & 15);
  int jc  = lf >> 4;
  const float* p = src + (long)row * KD + kt * 32 + jc * 8;
  float4 v0 = *(const float4*)p;
  float4 v1 = *(const float4*)(p + 4);
  s16x8 o;
  o[0]=(short)f2bf(v0.x); o[1]=(short)f2bf(v0.y); o[2]=(short)f2bf(v0.z); o[3]=(short)f2bf(v0.w);
  o[4]=(short)f2bf(v1.x); o[5]=(short)f2bf(v1.y); o[6]=(short)f2bf(v1.z); o[7]=(short)f2bf(v1.w);
  *(s16x8*)(dst + ((long)mt * 16 + kt) * 512 + (long)lf * 8) = o;
}

// ---------- kernel: weights fp32 -> bf16 fragment layout (rows 0..511 wq, 512..1023 wk) ----------
__global__ __launch_bounds__(256)
void k_convw(const float* __restrict__ wq, const float* __restrict__ wk,
             unsigned short* __restrict__ Wf) {
  int gid = blockIdx.x * 256 + threadIdx.x;   // 65536 threads
  int nt = gid >> 10, slot = gid & 1023;
  int kt = slot >> 6, lf = slot & 63;
  int f  = nt * 16 + (lf & 15);
  int jc = lf >> 4;
  const float* p = ((f < 512) ? (wq + (long)f * KD) : (wk + (long)(f - 512) * KD)) + kt * 32 + jc * 8;
  float4 v0 = *(const float4*)p;
  float4 v1 = *(const float4*)(p + 4);
  s16x8 o;
  o[0]=(short)f2bf(v0.x); o[1]=(short)f2bf(v0.y); o[2]=(short)f2bf(v0.z); o[3]=(short)f2bf(v0.w);
  o[4]=(short)f2bf(v1.x); o[5]=(short)f2bf(v1.y); o[6]=(short)f2bf(v1.z); o[7]=(short)f2bf(v1.w);
  *(s16x8*)(Wf + ((long)nt * 16 + kt) * 512 + (long)lf * 8) = o;
}

// ---------- kernel: QK = A @ [Wq^T | Wk^T] + bias ----------
// v10: R10 skeleton, 128x64 tile. All prior schedule variants (R9/R10/R12/R13/R14)
// pinned at ~240 us with <=3.2 blocks/CU -- latency-bound with too few independent
// barrier groups. Shrinking acc to 2x4 (32 AGPR, ~82 regs/wave) + 24 KB LDS gives
// 5 blocks/CU (62% occ): 5 independent blocks cover each other's staging drains.
__global__ __launch_bounds__(256, 5)
void k_gemm(const unsigned short* __restrict__ Af, const unsigned short* __restrict__ Wf,
            const float* __restrict__ bq, const float* __restrict__ bk,
            unsigned short* __restrict__ QK) {
  __shared__ unsigned short Abuf[2][8 * 512];   // 8 m-frags per buffer (BK=32)
  __shared__ unsigned short Bbuf[2][4 * 512];   // 4 n-frags per buffer

  const int tid  = threadIdx.x;
  const int lane = tid & 63;
  const int wid  = tid >> 6;      // 0..3; wave owns m-frags {2*wid, 2*wid+1} x 4 n-frags
  const int rlo  = lane & 15, rhi = lane >> 4;

  // XCD-chunked swizzle; nwg = 1216*16 (multiple of 8) -> bijective.
  // 16 consecutive L share one mb -> A panel L2-resident per XCD run.
  const int cpx = gridDim.x >> 3;
  const int L   = (blockIdx.x & 7) * cpx + (blockIdx.x >> 3);
  const int mb  = L >> 4;
  const int bn  = L & 15;

#define STAGE(T, BUF) do { \
    if (wid < 2) { \
      _Pragma("unroll") for (int s = 0; s < 4; ++s) { \
        int msub = wid * 4 + s; \
        const unsigned short* g = Af + ((long)(mb * 8 + msub) * 16 + (T)) * 512 + lane * 8; \
        GLL16(g, &Abuf[(BUF)][msub * 512]); \
      } \
    } else if (wid == 2) { \
      _Pragma("unroll") for (int s = 0; s < 4; ++s) { \
        const unsigned short* g = Wf + ((long)(bn * 4 + s) * 16 + (T)) * 512 + lane * 8; \
        GLL16(g, &Bbuf[(BUF)][s * 512]); \
      } \
    } \
  } while (0)

  f32x4 acc[2][4] = {};
  STAGE(0, 0);
  __syncthreads();   // vmcnt(0) drain: buf0 ready

#pragma unroll 1
  for (int t = 0; t < 16; ++t) {
    const int cur = t & 1;
    if (t < 15) STAGE(t + 1, cur ^ 1);   // in flight across the compute phase

    s16x8 af[2], bfr[4];
#pragma unroll
    for (int m = 0; m < 2; ++m)
      af[m] = *(const s16x8*)&Abuf[cur][(wid * 2 + m) * 512 + lane * 8];
#pragma unroll
    for (int n = 0; n < 4; ++n)
      bfr[n] = *(const s16x8*)&Bbuf[cur][n * 512 + lane * 8];
#pragma unroll
    for (int m = 0; m < 2; ++m)
#pragma unroll
      for (int n = 0; n < 4; ++n)
        acc[m][n] = __builtin_amdgcn_mfma_f32_16x16x32_bf16(af[m], bfr[n], acc[m][n], 0, 0, 0);

    if (t < 15) __syncthreads();
  }
#undef STAGE

  // ---- epilogue: bias + bf16 store ----
#pragma unroll
  for (int n = 0; n < 4; ++n) {
    int colg = bn * 64 + n * 16 + rlo;
    float bias = (colg < 512) ? bq[colg] : bk[colg - 512];
#pragma unroll
    for (int m = 0; m < 2; ++m) {
      long rl = (long)mb * 128 + wid * 32 + m * 16 + (rhi << 2);
#pragma unroll
      for (int j = 0; j < 4; ++j)
        QK[(rl + j) * 1024 + colg] = f2bf(acc[m][n][j] + bias);
    }
  }
}

// ---------- kernel: per-group attention (swapped-QK^T, row-local softmax) ----------
// v3 (R13, verified): mfma(K,Q) puts q-row in lane; reduction = in-lane + 2 shfl_xor.
__global__ __launch_bounds__(256, 4)
void k_attn(const unsigned short* __restrict__ QK, float* __restrict__ acc, int g0) {
  __shared__ unsigned short Qs[19][1032];   // padded stride
  __shared__ float red[4];

  const int tid  = threadIdx.x;
  const int lane = tid & 63;
  const int wid  = tid >> 6;
  const long gl  = blockIdx.x;

  const unsigned short* src = QK + gl * 19 * 1024;
  for (int c = tid; c < 2432; c += 256) {
    int row = c >> 7, c8 = (c & 127) << 3;
    *(s16x8*)&Qs[row][c8] = *(const s16x8*)(src + row * 1024 + c8);
  }
  __syncthreads();

  const int rlo = lane & 15, rhi = lane >> 4;
  const s16x8 z8 = {};
  float psum = 0.f;

#pragma unroll
  for (int hh = 0; hh < 2; ++hh) {
    const int h = wid * 2 + hh;
    f32x4 s[2][2] = {};   // [k-tile mi][q-tile nj]
#pragma unroll
    for (int ks = 0; ks < 2; ++ks) {
      s16x8 qa[2], kb[2];
#pragma unroll
      for (int mi = 0; mi < 2; ++mi) {
        int r = mi * 16 + rlo;
        qa[mi] = (r < 19) ? *(const s16x8*)&Qs[r][h * 64 + ks * 32 + rhi * 8] : z8;
        kb[mi] = (r < 19) ? *(const s16x8*)&Qs[r][512 + h * 64 + ks * 32 + rhi * 8] : z8;
      }
#pragma unroll
      for (int mi = 0; mi < 2; ++mi)
#pragma unroll
        for (int nj = 0; nj < 2; ++nj)
          s[mi][nj] = __builtin_amdgcn_mfma_f32_16x16x32_bf16(kb[mi], qa[nj], s[mi][nj], 0, 0, 0);
    }

    // lane view: q = nj*16 + rlo; k = mi*16 + rhi*4 + j
#pragma unroll
    for (int nj = 0; nj < 2; ++nj) {
      const int q = nj * 16 + rlo;
      const bool qv = (q < 19);
      const bool wv = (rhi == 0);          // k=16..18 live on rhi==0
      float v0 = s[0][nj][0] * 0.125f;
      float v1 = s[0][nj][1] * 0.125f;
      float v2 = s[0][nj][2] * 0.125f;
      float v3 = s[0][nj][3] * 0.125f;
      float w0 = s[1][nj][0] * 0.125f;
      float w1 = s[1][nj][1] * 0.125f;
      float w2 = s[1][nj][2] * 0.125f;
      float mm = fmaxf(fmaxf(v0, v1), fmaxf(v2, v3));
      if (wv) mm = fmaxf(mm, fmaxf(fmaxf(w0, w1), w2));
      mm = fmaxf(mm, __shfl_xor(mm, 16));
      mm = fmaxf(mm, __shfl_xor(mm, 32));
      float e0 = __expf(v0 - mm), e1 = __expf(v1 - mm);
      float e2 = __expf(v2 - mm), e3 = __expf(v3 - mm);
      float se = e0 + e1 + e2 + e3;
      int k0 = rhi * 4;
      float ue = ((k0 > q) ? e0 : 0.f) + ((k0 + 1 > q) ? e1 : 0.f)
               + ((k0 + 2 > q) ? e2 : 0.f) + ((k0 + 3 > q) ? e3 : 0.f);
      if (wv) {
        float f0 = __expf(w0 - mm), f1 = __expf(w1 - mm), f2 = __expf(w2 - mm);
        se += f0 + f1 + f2;
        ue += ((16 > q) ? f0 : 0.f) + ((17 > q) ? f1 : 0.f) + ((18 > q) ? f2 : 0.f);
      }
      se += __shfl_xor(se, 16); se += __shfl_xor(se, 32);
      ue += __shfl_xor(ue, 16); ue += __shfl_xor(ue, 32);
      if (qv && rhi == 0) psum += ue / se;
    }
  }

  psum += __shfl_xor(psum, 1);
  psum += __shfl_xor(psum, 2);
  psum += __shfl_xor(psum, 4);
  psum += __shfl_xor(psum, 8);
  psum += __shfl_xor(psum, 16);
  psum += __shfl_xor(psum, 32);
  if (lane == 0) red[wid] = psum;
  __syncthreads();
  if (tid == 0) {
    int b = (g0 + (int)blockIdx.x) >> 9;
    atomicAdd(&acc[b], red[0] + red[1] + red[2] + red[3]);
  }
}

// ---------- kernel: finalize out[b] = clip(acc[b] / (8*171*512), 0, 1) ----------
__global__ void k_fin(const float* __restrict__ acc, float* __restrict__ out) {
  int t = threadIdx.x;
  if (t < 16) {
    float v = acc[t] * (1.0f / 700416.0f);
    out[t] = fminf(1.0f, fmaxf(0.0f, v));
  }
}

// ---------- host ----------
extern "C" void kernel_launch(void* const* d_in, const int* in_sizes, int n_in,
                              void* d_out, int out_size, void* d_ws, size_t ws_size,
                              hipStream_t stream) {
  const float* eeg = (const float*)d_in[0];
  const float* wq  = (const float*)d_in[1];
  const float* wk  = (const float*)d_in[2];
  const float* bq  = (const float*)d_in[3];
  const float* bk  = (const float*)d_in[4];
  float* out = (float*)d_out;

  char* ws = (char*)d_ws;
  unsigned short* Wf = (unsigned short*)ws;          // 1 MiB frag-layout weights
  float* acc = (float*)(ws + (1 << 20));             // 64 B accumulators
  long off = (1 << 20) + 256;

  // per-group: Af 19456 B, QK 38912 B. Single chunk when ws permits (R7 lesson).
  long avail = (long)ws_size - off;
  long G = avail / 58368;
  G = (G / 128) * 128;
  if (G > 8192) G = 8192;
  if (G < 128) G = 128;
  unsigned short* Afb = (unsigned short*)(ws + off);
  unsigned short* QKb = (unsigned short*)(ws + off + G * 19456L);

  hipMemsetAsync(acc, 0, 64, stream);
  k_convw<<<256, 256, 0, stream>>>(wq, wk, Wf);

  for (int g0 = 0; g0 < 8192; g0 += (int)G) {
    int cg = 8192 - g0; if (cg > (int)G) cg = (int)G;
    int rows   = cg * 19;            // cg multiple of 128 -> rows multiple of 2432
    int mtiles = rows / 16;
    k_conva<<<mtiles * 4, 256, 0, stream>>>(eeg + (long)g0 * 19 * KD, Afb);
    k_gemm<<<(rows / 128) * 16, 256, 0, stream>>>(Afb, Wf, bq, bk, QKb);
    k_attn<<<cg, 256, 0, stream>>>(QKb, acc, g0);
  }
  k_fin<<<1, 64, 0, stream>>>(acc, out);
}